// Round 8
// baseline (146.064 us; speedup 1.0000x reference)
//
#include <hip/hip_runtime.h>
#include <math.h>

// GCN graph-matching net. Verified reductions (R0-R6, absmax ~0):
//  - K off-diag values only used via (K != 0) -> class-match pattern; edge MLPs dead.
//  - normA @ u collapses to O(N) inclusion-exclusion; x stays rank<=7.
//  - Multiplicative sinkhorn: A = 2^(t - rowmax) once; steps u=1/(Av), v=1/(A^T u).
// R7: BARRIER-FREE sinkhorn on a single wave. R6 counters: ~1000 cyc per barrier-separated
//   step at ~2 GHz -> the s_barrier round-trip dominates. Wave 0 holds A (row/lane) and A^T
//   (col/lane) in registers (128 VGPR); u/v exchanged through LDS with same-wave lockstep
//   ordering (no s_barrier). 20 steps = 0 barriers. Handoff: t written both orientations to
//   LDS; s0/s1/out reconstructed by all 256 threads from (rm,u,v)+t. matvecB split into two
//   single-vector passes so normA(v0) folds into the t1/sacc bases before sinkhorn0 (keeps
//   register pressure under 256 for wave 0). Total workgroup barriers: 68 -> 13.

#define SK_SCALE 28.853900817779268f   // (1/TAU = 20) * log2(e)

template<int CTRL>
__device__ __forceinline__ float dppf(float x) {
    int xi = __float_as_int(x);
    int rr = __builtin_amdgcn_update_dpp(xi, xi, CTRL, 0xF, 0xF, false);
    return __int_as_float(rr);
}
__device__ __forceinline__ float quad_sum(float v) {   // sum over lane&3 quad
    v += dppf<0xB1>(v); v += dppf<0x4E>(v); return v;
}
__device__ __forceinline__ float e2f(float x) { return __builtin_amdgcn_exp2f(x); }
__device__ __forceinline__ float rcpf(float x) { return __builtin_amdgcn_rcpf(x); }
__device__ __forceinline__ float dot4(const float4 a, const float4 b) {
    return a.x*b.x + a.y*b.y + a.z*b.z + a.w*b.w;
}
__device__ __forceinline__ void fma4(float4& a, float b, const float4 c) {
    a.x += b*c.x; a.y += b*c.y; a.z += b*c.z; a.w += b*c.w;
}
__device__ __forceinline__ void add4(float4& a, const float4 c) {
    a.x += c.x; a.y += c.y; a.z += c.z; a.w += c.w;
}
__device__ __forceinline__ void ld16(const float* p, float* o) {
    #pragma unroll
    for (int t = 0; t < 4; ++t) {
        float4 v = *(const float4*)(p + 4*t);
        o[4*t+0]=v.x; o[4*t+1]=v.y; o[4*t+2]=v.z; o[4*t+3]=v.w;
    }
}
__device__ __forceinline__ float sum16(const float* a) {
    float s0=0,s1=0,s2=0,s3=0;
    #pragma unroll
    for (int t = 0; t < 4; ++t) {
        s0 += a[4*t+0]; s1 += a[4*t+1]; s2 += a[4*t+2]; s3 += a[4*t+3];
    }
    return (s0+s1)+(s2+s3);
}

// ---- Single-wave multiplicative sinkhorn: 20 steps, ZERO barriers. ----
// Wave 0 only. An: t natural (row-major, stride 68, SK_SCALE applied);
// At: t transposed. Leaves rm, final u (it18), v (it19) in srm/su/sv.
// Same-wave LDS ordering: one ds_write updates all 64 entries before later reads.
__device__ void sk_wave(const float* An, const float* At, int lane,
                        float* su, float* sv, float* srm) {
    float a[64], b[64];
    #pragma unroll
    for (int t = 0; t < 16; ++t) {
        float4 x = *(const float4*)(An + lane * 68 + 4 * t);
        a[4*t+0]=x.x; a[4*t+1]=x.y; a[4*t+2]=x.z; a[4*t+3]=x.w;
    }
    #pragma unroll
    for (int t = 0; t < 16; ++t) {
        float4 y = *(const float4*)(At + lane * 68 + 4 * t);
        b[4*t+0]=y.x; b[4*t+1]=y.y; b[4*t+2]=y.z; b[4*t+3]=y.w;
    }
    float m0 = fmaxf(a[0], a[1]), m1 = fmaxf(a[2], a[3]);
    #pragma unroll
    for (int j = 4; j < 64; j += 4) {
        m0 = fmaxf(m0, fmaxf(a[j], a[j+1]));
        m1 = fmaxf(m1, fmaxf(a[j+2], a[j+3]));
    }
    const float rm = fmaxf(m0, m1);
    float s0=0, s1=0, s2=0, s3=0;
    #pragma unroll
    for (int j = 0; j < 64; j += 4) {
        a[j]   = e2f(a[j]   - rm); s0 += a[j];
        a[j+1] = e2f(a[j+1] - rm); s1 += a[j+1];
        a[j+2] = e2f(a[j+2] - rm); s2 += a[j+2];
        a[j+3] = e2f(a[j+3] - rm); s3 += a[j+3];
    }
    float u = rcpf((s0 + s1) + (s2 + s3));   // it0 (row, v = 1)
    srm[lane] = rm;
    su[lane]  = u;
    #pragma unroll
    for (int t = 0; t < 16; ++t) {           // A^T factors need rm[i] per row i
        float4 rv = *(const float4*)(srm + 4 * t);
        b[4*t+0] = e2f(b[4*t+0] - rv.x);
        b[4*t+1] = e2f(b[4*t+1] - rv.y);
        b[4*t+2] = e2f(b[4*t+2] - rv.z);
        b[4*t+3] = e2f(b[4*t+3] - rv.w);
    }
    float v;
    {   // it1 (col)
        float c0=0,c1=0,c2=0,c3=0;
        #pragma unroll
        for (int t = 0; t < 16; ++t) {
            float4 uv = *(const float4*)(su + 4 * t);
            c0 += b[4*t+0]*uv.x; c1 += b[4*t+1]*uv.y;
            c2 += b[4*t+2]*uv.z; c3 += b[4*t+3]*uv.w;
        }
        v = rcpf((c0 + c1) + (c2 + c3));
        sv[lane] = v;
    }
    #pragma unroll 1
    for (int p = 0; p < 9; ++p) {            // its 2..19
        {   // row
            float c0=0,c1=0,c2=0,c3=0;
            #pragma unroll
            for (int t = 0; t < 16; ++t) {
                float4 vv = *(const float4*)(sv + 4 * t);
                c0 += a[4*t+0]*vv.x; c1 += a[4*t+1]*vv.y;
                c2 += a[4*t+2]*vv.z; c3 += a[4*t+3]*vv.w;
            }
            u = rcpf((c0 + c1) + (c2 + c3));
            su[lane] = u;
        }
        {   // col
            float c0=0,c1=0,c2=0,c3=0;
            #pragma unroll
            for (int t = 0; t < 16; ++t) {
                float4 uv = *(const float4*)(su + 4 * t);
                c0 += b[4*t+0]*uv.x; c1 += b[4*t+1]*uv.y;
                c2 += b[4*t+2]*uv.z; c3 += b[4*t+3]*uv.w;
            }
            v = rcpf((c0 + c1) + (c2 + c3));
            sv[lane] = v;
        }
    }
}

// Reconstruct s = coef * A.*u.*v in both orientations from LDS t + (rm,u,v).
__device__ __forceinline__ void recon_s(const float* A, const float* B,
        const float* su, const float* sv, const float* srm,
        int q, int r, float coef, float* sn, float* st) {
    float tA[16], tB[16], uq[16], vq[16], rmq[16];
    ld16(A + r*68 + 16*q, tA); ld16(B + r*68 + 16*q, tB);
    ld16(su + 16*q, uq); ld16(sv + 16*q, vq); ld16(srm + 16*q, rmq);
    const float cu = coef * su[r] * 1.0f;
    const float cv = coef * sv[r];
    const float rmr = srm[r];
    #pragma unroll
    for (int m = 0; m < 16; ++m) {
        sn[m] = e2f(tA[m] - rmr) * cu * vq[m];
        st[m] = e2f(tB[m] - rmq[m]) * uq[m] * cv;
    }
}

// normA matvec, single vector, both orientations, ONE barrier.
__device__ __forceinline__ void matvec_one(const float* u1, const float* u1t,
        const float* mmq, const float* dqv, const float* mmt, const float* dqt,
        float* o1, float* o1t, int q, int r, float* WR, float* WC) {
    float rs = 0, cs = 0;
    #pragma unroll
    for (int m = 0; m < 16; ++m) {
        rs += mmq[m] * dqv[m] * u1[m];
        cs += mmt[m] * dqt[m] * u1t[m];
    }
    rs = quad_sum(rs); cs = quad_sum(cs);
    if (q == 0) { WR[r] = rs; WC[r] = cs; }
    __syncthreads();
    float wr[16], wc[16];
    ld16(WR + 16*q, wr); ld16(WC + 16*q, wc);
    float W = quad_sum(sum16(wc));
    #pragma unroll
    for (int m = 0; m < 16; ++m) {
        float d = dqv[m], mm = mmq[m];
        float z = mm * d * u1[m];
        o1[m] = d * ((1.0f+mm)*d*u1[m] + mm*(W - rs - wc[m] + z));
        float dt = dqt[m], mt = mmt[m];
        float zt = mt * dt * u1t[m];
        o1t[m] = dt * ((1.0f+mt)*dt*u1t[m] + mt*(W - wr[m] - cs + zt));
    }
}

// normA matvec, dual vectors (u2==nullptr -> ones), ONE barrier.
__device__ __forceinline__ void matvec_dual(const float* u1, const float* u1t,
        const float* mmq, const float* dqv, const float* mmt, const float* dqt,
        float* o1, float* o1t, float* o2, float* o2t, int q, int r,
        float* WR1, float* WC1, float* WR2, float* WC2) {
    float rs1=0, rs2=0, cs1=0, cs2=0;
    #pragma unroll
    for (int m = 0; m < 16; ++m) {
        float md = mmq[m]*dqv[m], mdt = mmt[m]*dqt[m];
        rs1 += md * u1[m];  cs1 += mdt * u1t[m];
        rs2 += md;          cs2 += mdt;
    }
    rs1 = quad_sum(rs1); rs2 = quad_sum(rs2);
    cs1 = quad_sum(cs1); cs2 = quad_sum(cs2);
    if (q == 0) { WR1[r]=rs1; WR2[r]=rs2; WC1[r]=cs1; WC2[r]=cs2; }
    __syncthreads();
    float wr1[16], wc1[16], wr2[16], wc2[16];
    ld16(WR1 + 16*q, wr1); ld16(WC1 + 16*q, wc1);
    ld16(WR2 + 16*q, wr2); ld16(WC2 + 16*q, wc2);
    float W1 = quad_sum(sum16(wc1));
    float W2 = quad_sum(sum16(wc2));
    #pragma unroll
    for (int m = 0; m < 16; ++m) {
        float d = dqv[m], mm = mmq[m];
        float z1 = mm*d*u1[m], z2 = mm*d;
        o1[m] = d*((1.0f+mm)*d*u1[m] + mm*(W1 - rs1 - wc1[m] + z1));
        o2[m] = d*((1.0f+mm)*d       + mm*(W2 - rs2 - wc2[m] + z2));
        float dt = dqt[m], mt = mmt[m];
        float z1t = mt*dt*u1t[m], z2t = mt*dt;
        o1t[m] = dt*((1.0f+mt)*dt*u1t[m] + mt*(W1 - wr1[m] - cs1 + z1t));
        o2t[m] = dt*((1.0f+mt)*dt       + mt*(W2 - wr2[m] - cs2 + z2t));
    }
}

// Rebuild mm/dinv (cheap) from persistent LDS tables — avoids keeping them live
// across the wave-0 sinkhorn call (register pressure).
__device__ __forceinline__ void build_mmdq(const float* cls1, const float* cls2,
        const float* Dr, const float* Dc, int q, int r,
        float* mmq, float* mmt, float* dqv, float* dqt) {
    float c2q[16], c1q[16], dcq[16], drq[16];
    ld16(cls2 + 16*q, c2q); ld16(cls1 + 16*q, c1q);
    ld16(Dc + 16*q, dcq);   ld16(Dr + 16*q, drq);
    const float cls1r = cls1[r], cls2r = cls2[r];
    const float Drr = Dr[r], Dcr = Dc[r];
    float Tdeg = quad_sum(sum16(dcq));
    #pragma unroll
    for (int m = 0; m < 16; ++m) {
        mmq[m] = (cls1r == c2q[m]) ? 1.0f : 0.0f;
        mmt[m] = (c1q[m] == cls2r) ? 1.0f : 0.0f;
        dqv[m] = (mmq[m] != 0.0f) ? (1.0f / sqrtf(Tdeg - Drr - dcq[m] + 3.0f)) : 1.0f;
        dqt[m] = (mmt[m] != 0.0f) ? (1.0f / sqrtf(Tdeg - drq[m] - Dcr + 3.0f)) : 1.0f;
    }
}

extern "C" __global__ __launch_bounds__(256, 1)
void gcn_match_kernel(const float* ego, const float* cav,
                      const float* nw1, const float* nb1, const float* nw2, const float* nb2,
                      const float* sw0, const float* sb0, const float* cw0, const float* cb0,
                      const float* kw0, const float* kb0,
                      const float* sw1, const float* sb1, const float* cw1, const float* cb1,
                      const float* kw1, const float* kb1,
                      const float* fcw, const float* fcb,
                      float* out) {
    __shared__ __align__(16) float sh_hT1[64 * 68];   // ego h^T | dots | t natural (sh_A)
    __shared__ __align__(16) float sh_hT2[64 * 68];   // cav h^T | dots^T | t transposed (sh_B)
    __shared__ __align__(16) float sh_w2[2048];
    __shared__ __align__(16) float sh_f1[64 * 36];
    __shared__ __align__(16) float sh_f2[64 * 36];
    __shared__ __align__(16) float sh_nw1[320];
    __shared__ __align__(16) float sh_nb1[64], sh_nb2[32];
    __shared__ __align__(16) float sh_cls1[64], sh_cf1[64], sh_cls2[64], sh_cf2[64];
    __shared__ __align__(16) float sh_n1[64], sh_n2[64], sh_Dr[64], sh_Dc[64];
    __shared__ __align__(16) float sh_u[64], sh_v[64], sh_rm[64];
    __shared__ __align__(16) float sh_WR1[64], sh_WC1[64], sh_WR2[64], sh_WC2[64];
    __shared__ __align__(16) float sh_WR3[64], sh_WC3[64];
    __shared__ __align__(16) float sh_sw0[16], sh_sb0[16], sh_cw0[16], sh_cb0[16];
    __shared__ __align__(16) float sh_sb1[16], sh_cb1[16];
    __shared__ __align__(16) float sh_sw1[256], sh_cw1[256];
    __shared__ __align__(16) float sh_kw0[16], sh_kw1[16], sh_fcw[16];
    __shared__ float sh_kb[4];
    __shared__ float sh_avec[7 * 16];
    __shared__ float sh_coef[18];

    const int tid = threadIdx.x;
    const int wv = tid >> 6, lane = tid & 63;
    const int r = tid >> 2, q = tid & 3;
    float* sh_A = sh_hT1;
    float* sh_B = sh_hT2;

    // ================= P0a: stage everything =================
    ((float4*)sh_w2)[tid]       = ((const float4*)nw2)[tid];
    ((float4*)sh_w2)[tid + 256] = ((const float4*)nw2)[tid + 256];
    if (tid < 80)       ((float4*)sh_nw1)[tid]      = ((const float4*)nw1)[tid];
    else if (tid < 96)  ((float4*)sh_nb1)[tid-80]   = ((const float4*)nb1)[tid-80];
    else if (tid < 104) ((float4*)sh_nb2)[tid-96]   = ((const float4*)nb2)[tid-96];
    else if (tid < 108) ((float4*)sh_sw0)[tid-104]  = ((const float4*)sw0)[tid-104];
    else if (tid < 112) ((float4*)sh_sb0)[tid-108]  = ((const float4*)sb0)[tid-108];
    else if (tid < 116) ((float4*)sh_cw0)[tid-112]  = ((const float4*)cw0)[tid-112];
    else if (tid < 120) ((float4*)sh_cb0)[tid-116]  = ((const float4*)cb0)[tid-116];
    else if (tid < 124) ((float4*)sh_sb1)[tid-120]  = ((const float4*)sb1)[tid-120];
    else if (tid < 128) ((float4*)sh_cb1)[tid-124]  = ((const float4*)cb1)[tid-124];
    else if (tid < 192) ((float4*)sh_sw1)[tid-128]  = ((const float4*)sw1)[tid-128];
    else                ((float4*)sh_cw1)[tid-192]  = ((const float4*)cw1)[tid-192];
    if (tid < 4)        ((float4*)sh_kw0)[tid]      = ((const float4*)kw0)[tid];
    else if (tid < 8)   ((float4*)sh_kw1)[tid-4]    = ((const float4*)kw1)[tid-4];
    else if (tid < 12)  ((float4*)sh_fcw)[tid-8]    = ((const float4*)fcw)[tid-8];
    else if (tid == 12) sh_kb[0] = kb0[0];
    else if (tid == 13) sh_kb[1] = kb1[0];
    else if (tid == 14) sh_kb[2] = fcb[0];
    if (tid < 64) { sh_cls1[tid] = ego[tid*8+6]; sh_cf1[tid] = ego[tid*8+7]; }
    else if (tid < 128) { int j = tid-64; sh_cls2[j] = cav[j*8+6]; sh_cf2[j] = cav[j*8+7]; }
    __syncthreads();

    // ================= P0b: hidden MLP (transposed store), 4 waves ==============
    {
        float4 ea = ((const float4*)ego)[lane*2], eb = ((const float4*)ego)[lane*2+1];
        float4 ca = ((const float4*)cav)[lane*2], cb = ((const float4*)cav)[lane*2+1];
        #pragma unroll
        for (int kk = 0; kk < 16; ++kk) {
            int k = 16*wv + kk;
            float b1 = sh_nb1[k];
            float w0 = sh_nw1[k],     w1 = sh_nw1[64+k], w2_ = sh_nw1[128+k];
            float w3 = sh_nw1[192+k], w4 = sh_nw1[256+k];
            sh_hT1[k*68 + lane] = fmaxf(b1 + ea.y*w0 + ea.z*w1 + ea.w*w2_ + eb.x*w3 + eb.y*w4, 0.0f);
            sh_hT2[k*68 + lane] = fmaxf(b1 + ca.y*w0 + ca.z*w1 + ca.w*w2_ + cb.x*w3 + cb.y*w4, 0.0f);
        }
    }
    __syncthreads();

    // ================= P1: GEMMs (waves 0,1) + avec/coef (wave 2) ===============
    if (wv < 2) {
        const float* HT = (wv == 0) ? sh_hT1 : sh_hT2;
        float* F  = (wv == 0) ? sh_f1 : sh_f2;
        float* NN = (wv == 0) ? sh_n1 : sh_n2;
        const int rr = lane >> 2, oq = lane & 3;
        float4 accA[4], accB[4];
        #pragma unroll
        for (int m = 0; m < 4; ++m) { accA[m] = make_float4(0,0,0,0); accB[m] = accA[m]; }
        #pragma unroll 4
        for (int k = 0; k < 64; ++k) {
            float4 hq = *(const float4*)(HT + k*68 + 4*rr);
            float4 wA = *(const float4*)(sh_w2 + k*32 + 4*oq);
            float4 wB = *(const float4*)(sh_w2 + k*32 + 16 + 4*oq);
            fma4(accA[0], hq.x, wA); fma4(accB[0], hq.x, wB);
            fma4(accA[1], hq.y, wA); fma4(accB[1], hq.y, wB);
            fma4(accA[2], hq.z, wA); fma4(accB[2], hq.z, wB);
            fma4(accA[3], hq.w, wA); fma4(accB[3], hq.w, wB);
        }
        float4 b2a = *(const float4*)(sh_nb2 + 4*oq);
        float4 b2b = *(const float4*)(sh_nb2 + 16 + 4*oq);
        float sq[4];
        #pragma unroll
        for (int m = 0; m < 4; ++m) {
            add4(accA[m], b2a); add4(accB[m], b2b);
            int row = 4*rr + m;
            *(float4*)(F + row*36 + 4*oq)      = accA[m];
            *(float4*)(F + row*36 + 16 + 4*oq) = accB[m];
            float q2 = dot4(accA[m], accA[m]) + dot4(accB[m], accB[m]);
            q2 += dppf<0xB1>(q2); q2 += dppf<0x4E>(q2);
            sq[m] = q2;
        }
        if (oq == 0) {
            #pragma unroll
            for (int m = 0; m < 4; ++m)
                NN[4*rr + m] = fmaxf(sqrtf(sq[m]), 1e-8f);
        }
    } else if (wv == 2) {
        if (lane < 16) {
            int o = lane;
            float ax=0, av=0, as_=0, aw=0, au=0, ae=0, a1=0;
            #pragma unroll
            for (int k = 0; k < 16; ++k) {
                float s0k = sh_sw0[k], c0k = sh_cw0[k], b0k = sh_sb0[k] + sh_cb0[k];
                float s1ko = sh_sw1[k*16+o], c1ko = sh_cw1[k*16+o];
                ax += s0k*s1ko;  av += c0k*s1ko + s0k*c1ko;  as_ += s1ko;
                aw += c0k*c1ko;  au += c1ko;  ae += b0k*c1ko;  a1 += b0k*s1ko;
            }
            a1 += sh_sb1[o] + sh_cb1[o];
            sh_avec[0*16+o]=ax; sh_avec[1*16+o]=av; sh_avec[2*16+o]=as_;
            sh_avec[3*16+o]=aw; sh_avec[4*16+o]=au; sh_avec[5*16+o]=ae;
            sh_avec[6*16+o]=a1;
        }
        if (lane < 18) {
            int t = lane; float c = 0.0f;
            if (t == 0)      { for (int k = 0; k < 16; ++k) c += sh_sw0[k]*sh_kw0[k]; }
            else if (t == 1) { for (int k = 0; k < 16; ++k) c += sh_cw0[k]*sh_kw0[k]; }
            else if (t == 2) { for (int k = 0; k < 16; ++k) c += (sh_sb0[k]+sh_cb0[k])*sh_kw0[k]; c += sh_kb[0]; }
            else if (t < 10) { int v = t-3;
                for (int o = 0; o < 16; ++o) c += sh_avec[v*16+o]*sh_kw1[o];
                if (v == 6) c += sh_kb[1];
            } else if (t < 17) { int v = t-10;
                for (int o = 0; o < 16; ++o) c += sh_avec[v*16+o]*sh_fcw[o];
                if (v == 6) c += sh_kb[2];
            } else { for (int o = 0; o < 16; ++o) c += sh_fcw[o]; }
            sh_coef[t] = c;
        }
    }
    __syncthreads();

    // ================= P2: dots (both orientations) + degrees =================
    {
        const int sc = lane & 15, rc = lane >> 4;
        float dt[4][4];
        #pragma unroll
        for (int m = 0; m < 4; ++m)
            #pragma unroll
            for (int k = 0; k < 4; ++k) dt[m][k] = 0.0f;
        for (int kq = 0; kq < 8; ++kq) {
            float4 f2q[4];
            #pragma unroll
            for (int k = 0; k < 4; ++k)
                f2q[k] = *(const float4*)(sh_f2 + (sc + 16*k)*36 + 4*kq);
            #pragma unroll
            for (int m = 0; m < 4; ++m) {
                int rrow = 16*m + 4*wv + rc;
                float4 f1q = *(const float4*)(sh_f1 + rrow*36 + 4*kq);
                #pragma unroll
                for (int k = 0; k < 4; ++k) dt[m][k] += dot4(f1q, f2q[k]);
            }
        }
        #pragma unroll
        for (int m = 0; m < 4; ++m) {
            int rrow = 16*m + 4*wv + rc;
            #pragma unroll
            for (int k = 0; k < 4; ++k) {
                sh_hT1[rrow*68 + sc + 16*k] = dt[m][k];       // dots natural
                sh_hT2[(sc + 16*k)*68 + rrow] = dt[m][k];     // dots transposed
            }
        }
    }
    {   // degrees (written once; persist for build_mmdq)
        float c2q[16], c1q[16];
        ld16(sh_cls2 + 16*q, c2q); ld16(sh_cls1 + 16*q, c1q);
        const float cls1r = sh_cls1[r], cls2r = sh_cls2[r];
        float dr = 0, dc = 0;
        #pragma unroll
        for (int m = 0; m < 16; ++m) {
            dr += (cls1r == c2q[m]) ? 1.0f : 0.0f;
            dc += (c1q[m] == cls2r) ? 1.0f : 0.0f;
        }
        dr = quad_sum(dr); dc = quad_sum(dc);
        if (q == 0) { sh_Dr[r] = dr; sh_Dc[r] = dc; }
    }
    __syncthreads();

    // ================= P3: mm/dinv + x0 (both orientations) =================
    float mmq[16], mmt[16], dqv[16], dqt[16];
    build_mmdq(sh_cls1, sh_cls2, sh_Dr, sh_Dc, q, r, mmq, mmt, dqv, dqt);
    float x0[16], x0t[16];
    {
        float f2v[16], f1v[16], n2q[16], n1q[16], dotq[16], dotTq[16];
        ld16(sh_cf2 + 16*q, f2v); ld16(sh_cf1 + 16*q, f1v);
        ld16(sh_n2 + 16*q, n2q);  ld16(sh_n1 + 16*q, n1q);
        ld16(sh_hT1 + r*68 + 16*q, dotq);
        ld16(sh_hT2 + r*68 + 16*q, dotTq);
        const float n1r = sh_n1[r], n2r = sh_n2[r];
        const float cf1r = sh_cf1[r], cf2r = sh_cf2[r];
        #pragma unroll
        for (int m = 0; m < 16; ++m) {
            x0[m]  = mmq[m] * sqrtf(cf1r * f2v[m]) * (dotq[m]  / (n1r * n2q[m]));
            x0t[m] = mmt[m] * sqrtf(f1v[m] * cf2r) * (dotTq[m] / (n1q[m] * n2r));
        }
    }

    // ======= matvec A (dual: x0 & ones) then matvec B1 (v0) — pre-sinkhorn ======
    float v0[16], v0t[16], oe[16], oet[16];
    matvec_dual(x0, x0t, mmq, dqv, mmt, dqt,
                v0, v0t, oe, oet, q, r, sh_WR1, sh_WC1, sh_WR2, sh_WC2);
    float ov[16], ovt[16];
    matvec_one(v0, v0t, mmq, dqv, mmt, dqt, ov, ovt, q, r, sh_WR3, sh_WC3);

    // ======= t0 + bases (x0/v0/oe/ov all folded -> dead before sinkhorn0) =======
    float t1b[16], t1bt[16], sbq[16], sbt[16];
    {
        float c0 = sh_coef[0], c1 = sh_coef[1], c2 = sh_coef[2];
        float ctx = sh_coef[3], ctv = sh_coef[4];
        float cw_ = sh_coef[6], ce_ = sh_coef[8], ct1 = sh_coef[9];
        float csx = sh_coef[10], csv = sh_coef[11];
        float cw2 = sh_coef[13], ce2 = sh_coef[15], cs1 = sh_coef[16];
        #pragma unroll
        for (int t = 0; t < 4; ++t) {
            float4 a4, b4;
            a4.x = (c0*x0[4*t+0] + c1*v0[4*t+0] + c2) * SK_SCALE;
            a4.y = (c0*x0[4*t+1] + c1*v0[4*t+1] + c2) * SK_SCALE;
            a4.z = (c0*x0[4*t+2] + c1*v0[4*t+2] + c2) * SK_SCALE;
            a4.w = (c0*x0[4*t+3] + c1*v0[4*t+3] + c2) * SK_SCALE;
            b4.x = (c0*x0t[4*t+0] + c1*v0t[4*t+0] + c2) * SK_SCALE;
            b4.y = (c0*x0t[4*t+1] + c1*v0t[4*t+1] + c2) * SK_SCALE;
            b4.z = (c0*x0t[4*t+2] + c1*v0t[4*t+2] + c2) * SK_SCALE;
            b4.w = (c0*x0t[4*t+3] + c1*v0t[4*t+3] + c2) * SK_SCALE;
            *(float4*)(sh_A + r*68 + 16*q + 4*t) = a4;   // t0 natural
            *(float4*)(sh_B + r*68 + 16*q + 4*t) = b4;   // t0 transposed
        }
        #pragma unroll
        for (int m = 0; m < 16; ++m) {
            t1b[m]  = ctx*x0[m]  + ctv*v0[m]  + ct1 + ce_*oe[m]  + cw_*ov[m];
            t1bt[m] = ctx*x0t[m] + ctv*v0t[m] + ct1 + ce_*oet[m] + cw_*ovt[m];
            sbq[m]  = csx*x0[m]  + csv*v0[m]  + cs1 + ce2*oe[m]  + cw2*ov[m];
            sbt[m]  = csx*x0t[m] + csv*v0t[m] + cs1 + ce2*oet[m] + cw2*ovt[m];
        }
    }
    __syncthreads();

    // ================= sinkhorn0 (wave 0, barrier-free) =================
    if (wv == 0) sk_wave(sh_A, sh_B, lane, sh_u, sh_v, sh_rm);
    __syncthreads();

    // ================= recon s0; matvec B2 (s0); t1 + sacc =================
    float s0v[16], s0t[16];
    recon_s(sh_A, sh_B, sh_u, sh_v, sh_rm, q, r, 1.0f, s0v, s0t);
    build_mmdq(sh_cls1, sh_cls2, sh_Dr, sh_Dc, q, r, mmq, mmt, dqv, dqt);
    float os[16], ost[16];
    matvec_one(s0v, s0t, mmq, dqv, mmt, dqt, os, ost, q, r, sh_WR1, sh_WC1);
    float sacc[16], sacct[16];
    {
        float cts = sh_coef[5], cu_ = sh_coef[7];
        float css = sh_coef[12], cu2 = sh_coef[14];
        #pragma unroll
        for (int t = 0; t < 4; ++t) {
            float4 a4, b4;
            #pragma unroll
            for (int e = 0; e < 4; ++e) {
                int m = 4*t + e;
                float tn = (t1b[m]  + cts*s0v[m] + cu_*os[m])  * SK_SCALE;
                float tt = (t1bt[m] + cts*s0t[m] + cu_*ost[m]) * SK_SCALE;
                (&a4.x)[e] = tn; (&b4.x)[e] = tt;
                sacc[m]  = sbq[m] + css*s0v[m] + cu2*os[m];
                sacct[m] = sbt[m] + css*s0t[m] + cu2*ost[m];
            }
            *(float4*)(sh_A + r*68 + 16*q + 4*t) = a4;   // t1 natural
            *(float4*)(sh_B + r*68 + 16*q + 4*t) = b4;   // t1 transposed
        }
    }
    __syncthreads();

    // ================= sinkhorn1 =================
    if (wv == 0) sk_wave(sh_A, sh_B, lane, sh_u, sh_v, sh_rm);
    __syncthreads();

    // ================= recon s1; sacc += c17*s1; handoff s = sacc^T =============
    {
        float s1v[16], s1t[16];
        recon_s(sh_A, sh_B, sh_u, sh_v, sh_rm, q, r, sh_coef[17], s1v, s1t);
        #pragma unroll
        for (int t = 0; t < 4; ++t) {
            float4 a4, b4;
            #pragma unroll
            for (int e = 0; e < 4; ++e) {
                int m = 4*t + e;
                sacc[m]  += s1v[m];
                sacct[m] += s1t[m];
                (&a4.x)[e] = sacct[m] * SK_SCALE;   // s natural row r = sacc^T
                (&b4.x)[e] = sacc[m] * SK_SCALE;    // s col r
            }
            *(float4*)(sh_A + r*68 + 16*q + 4*t) = a4;
            *(float4*)(sh_B + r*68 + 16*q + 4*t) = b4;
        }
    }
    __syncthreads();

    // ================= sinkhorn2 -> output =================
    if (wv == 0) sk_wave(sh_A, sh_B, lane, sh_u, sh_v, sh_rm);
    __syncthreads();
    {
        float tA[16], vq[16];
        ld16(sh_A + r*68 + 16*q, tA);
        ld16(sh_v + 16*q, vq);
        const float rmr = sh_rm[r], ur = sh_u[r];
        #pragma unroll
        for (int t = 0; t < 4; ++t) {
            float4 o4;
            o4.x = e2f(tA[4*t+0] - rmr) * ur * vq[4*t+0];
            o4.y = e2f(tA[4*t+1] - rmr) * ur * vq[4*t+1];
            o4.z = e2f(tA[4*t+2] - rmr) * ur * vq[4*t+2];
            o4.w = e2f(tA[4*t+3] - rmr) * ur * vq[4*t+3];
            *(float4*)(out + r*64 + 16*q + 4*t) = o4;
        }
    }
}

extern "C" void kernel_launch(void* const* d_in, const int* in_sizes, int n_in,
                              void* d_out, int out_size, void* d_ws, size_t ws_size,
                              hipStream_t stream) {
    const float* ego = (const float*)d_in[0];
    const float* cav = (const float*)d_in[1];
    const float* nw1 = (const float*)d_in[2];
    const float* nb1 = (const float*)d_in[3];
    const float* nw2 = (const float*)d_in[4];
    const float* nb2 = (const float*)d_in[5];
    // d_in[6..9] = edge MLP weights: dead code (edge values only feed the (K!=0) pattern)
    const float* sw0 = (const float*)d_in[10];
    const float* sb0 = (const float*)d_in[11];
    const float* cw0 = (const float*)d_in[12];
    const float* cb0 = (const float*)d_in[13];
    const float* kw0 = (const float*)d_in[14];
    const float* kb0 = (const float*)d_in[15];
    const float* sw1 = (const float*)d_in[16];
    const float* sb1 = (const float*)d_in[17];
    const float* cw1 = (const float*)d_in[18];
    const float* cb1 = (const float*)d_in[19];
    const float* kw1 = (const float*)d_in[20];
    const float* kb1 = (const float*)d_in[21];
    const float* fcw = (const float*)d_in[22];
    const float* fcb = (const float*)d_in[23];

    gcn_match_kernel<<<dim3(1), dim3(256), 0, stream>>>(
        ego, cav, nw1, nb1, nw2, nb2,
        sw0, sb0, cw0, cb0, kw0, kb0,
        sw1, sb1, cw1, cb1, kw1, kb1,
        fcw, fcb, (float*)d_out);
}

// Round 9
// 125.071 us; speedup vs baseline: 1.1678x; 1.1678x over previous
//
#include <hip/hip_runtime.h>
#include <math.h>

// GCN graph-matching net. Verified reductions (R0-R6, absmax ~0):
//  - K off-diag values only used via (K != 0) -> class-match pattern; edge MLPs dead.
//  - normA @ u collapses to O(N) inclusion-exclusion; x stays rank<=7.
//  - Multiplicative sinkhorn: A = 2^(t - rowmax) once; steps u=1/(Av), v=1/(A^T u).
// R6 (BEST, reverted to in R8): 4-wave kernel (256 threads). Thread (r=tid>>2, q=tid&3)
//   owns 16 row-elems and 16 col-elems. Reductions: sum16-in-thread + 2-op quad-DPP.
//   Dual-orientation registers; 1-barrier matvecs; 1-barrier sinkhorn steps.
// R7 (single-wave barrier-free sinkhorn) REGRESSED 40->63 us: VGPR 256 (spill pressure)
//   + zero latency hiding on the serial 16x ds_read chain with 3 waves idle. Reverted.
// Floor analysis: ~60 serially-dependent sinkhorn half-steps x ~1 LDS RAW round-trip
//   is algorithmically required by the reference's 3x20 alternating normalizations.

#define SK_SCALE 28.853900817779268f   // (1/TAU = 20) * log2(e)

template<int CTRL>
__device__ __forceinline__ float dppf(float x) {
    int xi = __float_as_int(x);
    int rr = __builtin_amdgcn_update_dpp(xi, xi, CTRL, 0xF, 0xF, false);
    return __int_as_float(rr);
}
__device__ __forceinline__ float quad_sum(float v) {   // sum over lane&3 quad
    v += dppf<0xB1>(v); v += dppf<0x4E>(v); return v;
}
__device__ __forceinline__ float quad_max(float v) {
    v = fmaxf(v, dppf<0xB1>(v)); v = fmaxf(v, dppf<0x4E>(v)); return v;
}
__device__ __forceinline__ float e2f(float x) { return __builtin_amdgcn_exp2f(x); }
__device__ __forceinline__ float rcpf(float x) { return __builtin_amdgcn_rcpf(x); }
__device__ __forceinline__ float dot4(const float4 a, const float4 b) {
    return a.x*b.x + a.y*b.y + a.z*b.z + a.w*b.w;
}
__device__ __forceinline__ void fma4(float4& a, float b, const float4 c) {
    a.x += b*c.x; a.y += b*c.y; a.z += b*c.z; a.w += b*c.w;
}
__device__ __forceinline__ void add4(float4& a, const float4 c) {
    a.x += c.x; a.y += c.y; a.z += c.z; a.w += c.w;
}
__device__ __forceinline__ void ld16(const float* p, float* o) {
    #pragma unroll
    for (int t = 0; t < 4; ++t) {
        float4 v = *(const float4*)(p + 4*t);
        o[4*t+0]=v.x; o[4*t+1]=v.y; o[4*t+2]=v.z; o[4*t+3]=v.w;
    }
}
__device__ __forceinline__ float dotsum16(const float* a, const float* b) {
    float s0=0,s1=0,s2=0,s3=0;
    #pragma unroll
    for (int t = 0; t < 4; ++t) {
        s0 += a[4*t+0]*b[4*t+0]; s1 += a[4*t+1]*b[4*t+1];
        s2 += a[4*t+2]*b[4*t+2]; s3 += a[4*t+3]*b[4*t+3];
    }
    return (s0+s1)+(s2+s3);
}
__device__ __forceinline__ float sum16(const float* a) {
    float s0=0,s1=0,s2=0,s3=0;
    #pragma unroll
    for (int t = 0; t < 4; ++t) {
        s0 += a[4*t+0]; s1 += a[4*t+1]; s2 += a[4*t+2]; s3 += a[4*t+3];
    }
    return (s0+s1)+(s2+s3);
}

// Multiplicative sinkhorn, 20 steps, 20 barriers. tq: row r, cols 16q+m (log2-domain,
// pre-scaled); tt: rows 16q+m, col r. Leaves A in aq/att, final u (it18) / v (it19).
__device__ __forceinline__ void sk_mult(const float* tq, const float* tt, int q, int r,
                                        float* up, float* vp, float* rmp,
                                        float* aq, float* att, float* u_out, float* v_out) {
    float rm = tq[0];
    #pragma unroll
    for (int m = 1; m < 16; ++m) rm = fmaxf(rm, tq[m]);
    rm = quad_max(rm);
    #pragma unroll
    for (int m = 0; m < 16; ++m) aq[m] = e2f(tq[m] - rm);
    float u = rcpf(quad_sum(sum16(aq)));          // it0 (row, v=1)
    if (q == 0) { rmp[r] = rm; up[r] = u; }
    __syncthreads();
    float rmq[16]; ld16(rmp + 16*q, rmq);
    #pragma unroll
    for (int m = 0; m < 16; ++m) att[m] = e2f(tt[m] - rmq[m]);
    float v;
    {   // it1 (col)
        float uq[16]; ld16(up + 16*q, uq);
        v = rcpf(quad_sum(dotsum16(att, uq)));
        if (q == 0) vp[r] = v;
        __syncthreads();
    }
    #pragma unroll 1
    for (int p = 0; p < 9; ++p) {                 // its 2..19
        float vq[16]; ld16(vp + 16*q, vq);
        u = rcpf(quad_sum(dotsum16(aq, vq)));
        if (q == 0) up[r] = u;
        __syncthreads();
        float uq[16]; ld16(up + 16*q, uq);
        v = rcpf(quad_sum(dotsum16(att, uq)));
        if (q == 0) vp[r] = v;
        __syncthreads();
    }
    *u_out = u; *v_out = v;
}

// normA matvec, dual vectors x dual orientations, ONE barrier. u2==nullptr -> ones.
__device__ __forceinline__ void matvec_dual(const float* u1, const float* u1t,
                                            const float* u2, const float* u2t,
                                            const float* mmq, const float* dqv,
                                            const float* mmt, const float* dqt,
                                            float* o1, float* o1t, float* o2, float* o2t,
                                            int q, int r,
                                            float* WR1, float* WC1, float* WR2, float* WC2) {
    float rs1=0, rs2=0, cs1=0, cs2=0;
    #pragma unroll
    for (int m = 0; m < 16; ++m) {
        float md = mmq[m]*dqv[m], mdt = mmt[m]*dqt[m];
        rs1 += md * u1[m];               cs1 += mdt * u1t[m];
        rs2 += md * (u2 ? u2[m] : 1.0f); cs2 += mdt * (u2t ? u2t[m] : 1.0f);
    }
    rs1 = quad_sum(rs1); rs2 = quad_sum(rs2);
    cs1 = quad_sum(cs1); cs2 = quad_sum(cs2);
    if (q == 0) { WR1[r]=rs1; WR2[r]=rs2; WC1[r]=cs1; WC2[r]=cs2; }
    __syncthreads();
    float wr1[16], wc1[16], wr2[16], wc2[16];
    ld16(WR1 + 16*q, wr1); ld16(WC1 + 16*q, wc1);
    ld16(WR2 + 16*q, wr2); ld16(WC2 + 16*q, wc2);
    float W1 = quad_sum(sum16(wc1));
    float W2 = quad_sum(sum16(wc2));
    #pragma unroll
    for (int m = 0; m < 16; ++m) {
        float d = dqv[m], mm = mmq[m];
        float u1m = u1[m], u2m = u2 ? u2[m] : 1.0f;
        float z1 = mm*d*u1m, z2 = mm*d*u2m;
        o1[m] = d*((1.0f+mm)*d*u1m + mm*(W1 - rs1 - wc1[m] + z1));
        o2[m] = d*((1.0f+mm)*d*u2m + mm*(W2 - rs2 - wc2[m] + z2));
        float dt = dqt[m], mt = mmt[m];
        float u1tm = u1t[m], u2tm = u2t ? u2t[m] : 1.0f;
        float z1t = mt*dt*u1tm, z2t = mt*dt*u2tm;
        o1t[m] = dt*((1.0f+mt)*dt*u1tm + mt*(W1 - wr1[m] - cs1 + z1t));
        o2t[m] = dt*((1.0f+mt)*dt*u2tm + mt*(W2 - wr2[m] - cs2 + z2t));
    }
}

extern "C" __global__ __launch_bounds__(256, 1)
void gcn_match_kernel(const float* ego, const float* cav,
                      const float* nw1, const float* nb1, const float* nw2, const float* nb2,
                      const float* sw0, const float* sb0, const float* cw0, const float* cb0,
                      const float* kw0, const float* kb0,
                      const float* sw1, const float* sb1, const float* cw1, const float* cb1,
                      const float* kw1, const float* kb1,
                      const float* fcw, const float* fcb,
                      float* out) {
    __shared__ __align__(16) float sh_hT1[64 * 68];   // ego h^T | later dots (natural)
    __shared__ __align__(16) float sh_hT2[64 * 68];   // cav h^T | later dots^T
    __shared__ __align__(16) float sh_w2[2048];
    __shared__ __align__(16) float sh_f1[64 * 36];
    __shared__ __align__(16) float sh_f2[64 * 36];
    __shared__ __align__(16) float sh_nw1[320];
    __shared__ __align__(16) float sh_nb1[64], sh_nb2[32];
    __shared__ __align__(16) float sh_cls1[64], sh_cf1[64], sh_cls2[64], sh_cf2[64];
    __shared__ __align__(16) float sh_n1[64], sh_n2[64], sh_Dr[64], sh_Dc[64];
    __shared__ __align__(16) float sh_up[64], sh_vp[64], sh_rmp[64];
    __shared__ __align__(16) float sh_WR1[64], sh_WC1[64], sh_WR2[64], sh_WC2[64];
    __shared__ __align__(16) float sh_sw0[16], sh_sb0[16], sh_cw0[16], sh_cb0[16];
    __shared__ __align__(16) float sh_sb1[16], sh_cb1[16];
    __shared__ __align__(16) float sh_sw1[256], sh_cw1[256];
    __shared__ __align__(16) float sh_kw0[16], sh_kw1[16], sh_fcw[16];
    __shared__ float sh_kb[4];        // kb0, kb1, fcb
    __shared__ float sh_avec[7 * 16];
    __shared__ float sh_coef[18];

    const int tid = threadIdx.x;
    const int wv = tid >> 6, lane = tid & 63;
    const int r = tid >> 2, q = tid & 3;

    // ================= P0a: stage everything (one parallel load round) ==========
    ((float4*)sh_w2)[tid]       = ((const float4*)nw2)[tid];
    ((float4*)sh_w2)[tid + 256] = ((const float4*)nw2)[tid + 256];
    if (tid < 80)       ((float4*)sh_nw1)[tid]      = ((const float4*)nw1)[tid];
    else if (tid < 96)  ((float4*)sh_nb1)[tid-80]   = ((const float4*)nb1)[tid-80];
    else if (tid < 104) ((float4*)sh_nb2)[tid-96]   = ((const float4*)nb2)[tid-96];
    else if (tid < 108) ((float4*)sh_sw0)[tid-104]  = ((const float4*)sw0)[tid-104];
    else if (tid < 112) ((float4*)sh_sb0)[tid-108]  = ((const float4*)sb0)[tid-108];
    else if (tid < 116) ((float4*)sh_cw0)[tid-112]  = ((const float4*)cw0)[tid-112];
    else if (tid < 120) ((float4*)sh_cb0)[tid-116]  = ((const float4*)cb0)[tid-116];
    else if (tid < 124) ((float4*)sh_sb1)[tid-120]  = ((const float4*)sb1)[tid-120];
    else if (tid < 128) ((float4*)sh_cb1)[tid-124]  = ((const float4*)cb1)[tid-124];
    else if (tid < 192) ((float4*)sh_sw1)[tid-128]  = ((const float4*)sw1)[tid-128];
    else                ((float4*)sh_cw1)[tid-192]  = ((const float4*)cw1)[tid-192];
    if (tid < 4)        ((float4*)sh_kw0)[tid]      = ((const float4*)kw0)[tid];
    else if (tid < 8)   ((float4*)sh_kw1)[tid-4]    = ((const float4*)kw1)[tid-4];
    else if (tid < 12)  ((float4*)sh_fcw)[tid-8]    = ((const float4*)fcw)[tid-8];
    else if (tid == 12) sh_kb[0] = kb0[0];
    else if (tid == 13) sh_kb[1] = kb1[0];
    else if (tid == 14) sh_kb[2] = fcb[0];
    if (tid < 64) { sh_cls1[tid] = ego[tid*8+6]; sh_cf1[tid] = ego[tid*8+7]; }
    else if (tid < 128) { int j = tid-64; sh_cls2[j] = cav[j*8+6]; sh_cf2[j] = cav[j*8+7]; }
    __syncthreads();

    // ================= P0b: hidden MLP (transposed store), 4 waves ==============
    {
        float4 ea = ((const float4*)ego)[lane*2], eb = ((const float4*)ego)[lane*2+1];
        float4 ca = ((const float4*)cav)[lane*2], cb = ((const float4*)cav)[lane*2+1];
        #pragma unroll
        for (int kk = 0; kk < 16; ++kk) {
            int k = 16*wv + kk;
            float b1 = sh_nb1[k];
            float w0 = sh_nw1[k],       w1 = sh_nw1[64+k],  w2_ = sh_nw1[128+k];
            float w3 = sh_nw1[192+k],   w4 = sh_nw1[256+k];
            sh_hT1[k*68 + lane] = fmaxf(b1 + ea.y*w0 + ea.z*w1 + ea.w*w2_ + eb.x*w3 + eb.y*w4, 0.0f);
            sh_hT2[k*68 + lane] = fmaxf(b1 + ca.y*w0 + ca.z*w1 + ca.w*w2_ + cb.x*w3 + cb.y*w4, 0.0f);
        }
    }
    __syncthreads();

    // ================= P1: GEMMs (waves 0,1) + avec/coef (wave 2) ===============
    if (wv < 2) {
        const float* HT = (wv == 0) ? sh_hT1 : sh_hT2;
        float* F  = (wv == 0) ? sh_f1 : sh_f2;
        float* NN = (wv == 0) ? sh_n1 : sh_n2;
        const int rr = lane >> 2, oq = lane & 3;
        float4 accA[4], accB[4];
        #pragma unroll
        for (int m = 0; m < 4; ++m) { accA[m] = make_float4(0,0,0,0); accB[m] = accA[m]; }
        #pragma unroll 4
        for (int k = 0; k < 64; ++k) {
            float4 hq = *(const float4*)(HT + k*68 + 4*rr);
            float4 wA = *(const float4*)(sh_w2 + k*32 + 4*oq);
            float4 wB = *(const float4*)(sh_w2 + k*32 + 16 + 4*oq);
            fma4(accA[0], hq.x, wA); fma4(accB[0], hq.x, wB);
            fma4(accA[1], hq.y, wA); fma4(accB[1], hq.y, wB);
            fma4(accA[2], hq.z, wA); fma4(accB[2], hq.z, wB);
            fma4(accA[3], hq.w, wA); fma4(accB[3], hq.w, wB);
        }
        float4 b2a = *(const float4*)(sh_nb2 + 4*oq);
        float4 b2b = *(const float4*)(sh_nb2 + 16 + 4*oq);
        float sq[4];
        #pragma unroll
        for (int m = 0; m < 4; ++m) {
            add4(accA[m], b2a); add4(accB[m], b2b);
            int row = 4*rr + m;
            *(float4*)(F + row*36 + 4*oq)      = accA[m];
            *(float4*)(F + row*36 + 16 + 4*oq) = accB[m];
            float q2 = dot4(accA[m], accA[m]) + dot4(accB[m], accB[m]);
            q2 += dppf<0xB1>(q2); q2 += dppf<0x4E>(q2);
            sq[m] = q2;
        }
        if (oq == 0) {
            #pragma unroll
            for (int m = 0; m < 4; ++m)
                NN[4*rr + m] = fmaxf(sqrtf(sq[m]), 1e-8f);
        }
    } else if (wv == 2) {
        if (lane < 16) {   // avec from LDS-staged weights
            int o = lane;
            float ax=0, av=0, as_=0, aw=0, au=0, ae=0, a1=0;
            #pragma unroll
            for (int k = 0; k < 16; ++k) {
                float s0k = sh_sw0[k], c0k = sh_cw0[k], b0k = sh_sb0[k] + sh_cb0[k];
                float s1ko = sh_sw1[k*16+o], c1ko = sh_cw1[k*16+o];
                ax += s0k*s1ko;  av += c0k*s1ko + s0k*c1ko;  as_ += s1ko;
                aw += c0k*c1ko;  au += c1ko;  ae += b0k*c1ko;  a1 += b0k*s1ko;
            }
            a1 += sh_sb1[o] + sh_cb1[o];
            sh_avec[0*16+o]=ax; sh_avec[1*16+o]=av; sh_avec[2*16+o]=as_;
            sh_avec[3*16+o]=aw; sh_avec[4*16+o]=au; sh_avec[5*16+o]=ae;
            sh_avec[6*16+o]=a1;
        }
        if (lane < 18) {   // coef (same wave: avec writes visible via lgkmcnt)
            int t = lane; float c = 0.0f;
            if (t == 0)      { for (int k = 0; k < 16; ++k) c += sh_sw0[k]*sh_kw0[k]; }
            else if (t == 1) { for (int k = 0; k < 16; ++k) c += sh_cw0[k]*sh_kw0[k]; }
            else if (t == 2) { for (int k = 0; k < 16; ++k) c += (sh_sb0[k]+sh_cb0[k])*sh_kw0[k]; c += sh_kb[0]; }
            else if (t < 10) { int v = t-3;
                for (int o = 0; o < 16; ++o) c += sh_avec[v*16+o]*sh_kw1[o];
                if (v == 6) c += sh_kb[1];
            } else if (t < 17) { int v = t-10;
                for (int o = 0; o < 16; ++o) c += sh_avec[v*16+o]*sh_fcw[o];
                if (v == 6) c += sh_kb[2];
            } else { for (int o = 0; o < 16; ++o) c += sh_fcw[o]; }
            sh_coef[t] = c;
        }
    }
    __syncthreads();

    // ================= P2: dots (all 4 waves, natural + transposed) + mm/degrees =
    {
        const int sc = lane & 15, rc = lane >> 4;
        float dt[4][4];
        #pragma unroll
        for (int m = 0; m < 4; ++m)
            #pragma unroll
            for (int k = 0; k < 4; ++k) dt[m][k] = 0.0f;
        for (int kq = 0; kq < 8; ++kq) {
            float4 f2q[4];
            #pragma unroll
            for (int k = 0; k < 4; ++k)
                f2q[k] = *(const float4*)(sh_f2 + (sc + 16*k)*36 + 4*kq);
            #pragma unroll
            for (int m = 0; m < 4; ++m) {
                int rrow = 16*m + 4*wv + rc;
                float4 f1q = *(const float4*)(sh_f1 + rrow*36 + 4*kq);
                #pragma unroll
                for (int k = 0; k < 4; ++k) dt[m][k] += dot4(f1q, f2q[k]);
            }
        }
        #pragma unroll
        for (int m = 0; m < 4; ++m) {
            int rrow = 16*m + 4*wv + rc;
            #pragma unroll
            for (int k = 0; k < 4; ++k) {
                sh_hT1[rrow*68 + sc + 16*k] = dt[m][k];       // dots natural
                sh_hT2[(sc + 16*k)*68 + rrow] = dt[m][k];     // dots transposed
            }
        }
    }
    float mmq[16], mmt[16], cfq[16], cft[16];
    float Drr, Dcr;
    {
        float c2q[16], c1q[16], f2v[16], f1v[16];
        ld16(sh_cls2 + 16*q, c2q); ld16(sh_cls1 + 16*q, c1q);
        ld16(sh_cf2 + 16*q, f2v);  ld16(sh_cf1 + 16*q, f1v);
        const float cls1r = sh_cls1[r], cls2r = sh_cls2[r];
        const float cf1r = sh_cf1[r],  cf2r  = sh_cf2[r];
        float dr = 0, dc = 0;
        #pragma unroll
        for (int m = 0; m < 16; ++m) {
            mmq[m] = (cls1r == c2q[m]) ? 1.0f : 0.0f;
            mmt[m] = (c1q[m] == cls2r) ? 1.0f : 0.0f;
            dr += mmq[m]; dc += mmt[m];
            cfq[m] = sqrtf(cf1r * f2v[m]);
            cft[m] = sqrtf(f1v[m] * cf2r);
        }
        Drr = quad_sum(dr);
        Dcr = quad_sum(dc);
        if (q == 0) { sh_Dr[r] = Drr; sh_Dc[r] = Dcr; }
    }
    __syncthreads();

    // ================= P3: dinv + x0, both orientations ==========================
    float dqv[16], dqt[16], x0[16], x0t[16];
    {
        float dcq[16], drq[16], n2q[16], n1q[16], dotq[16], dotTq[16];
        ld16(sh_Dc + 16*q, dcq); ld16(sh_Dr + 16*q, drq);
        ld16(sh_n2 + 16*q, n2q); ld16(sh_n1 + 16*q, n1q);
        ld16(sh_hT1 + r*68 + 16*q, dotq);
        ld16(sh_hT2 + r*68 + 16*q, dotTq);
        float Tdeg = quad_sum(sum16(dcq));
        const float n1r = sh_n1[r], n2r = sh_n2[r];
        #pragma unroll
        for (int m = 0; m < 16; ++m) {
            dqv[m] = (mmq[m] != 0.0f) ? (1.0f / sqrtf(Tdeg - Drr - dcq[m] + 3.0f)) : 1.0f;
            dqt[m] = (mmt[m] != 0.0f) ? (1.0f / sqrtf(Tdeg - drq[m] - Dcr + 3.0f)) : 1.0f;
            x0[m]  = mmq[m] * cfq[m] * (dotq[m]  / (n1r * n2q[m]));
            x0t[m] = mmt[m] * cft[m] * (dotTq[m] / (n1q[m] * n2r));
        }
    }

    // ================= matvec A: v0 = normA x0, oe = normA 1 =====================
    float v0[16], v0t[16], oe[16], oet[16];
    matvec_dual(x0, x0t, nullptr, nullptr, mmq, dqv, mmt, dqt,
                v0, v0t, oe, oet, q, r, sh_WR1, sh_WC1, sh_WR2, sh_WC2);

    // ================= t0 + fold x0/oe into t1/sacc bases ========================
    float t0q[16], t0t[16], t1b[16], t1bt[16], sbse[16], sbst[16];
    {
        float c0 = sh_coef[0], c1 = sh_coef[1], c2 = sh_coef[2];
        float ctx = sh_coef[3], ctv = sh_coef[4];
        float ce_ = sh_coef[8], ct1 = sh_coef[9];
        float csx = sh_coef[10], csv = sh_coef[11];
        float ce2 = sh_coef[15], cs1 = sh_coef[16];
        #pragma unroll
        for (int m = 0; m < 16; ++m) {
            t0q[m] = (c0*x0[m]  + c1*v0[m]  + c2) * SK_SCALE;
            t0t[m] = (c0*x0t[m] + c1*v0t[m] + c2) * SK_SCALE;
            t1b[m]  = ctx*x0[m]  + ctv*v0[m]  + ct1 + ce_*oe[m];
            t1bt[m] = ctx*x0t[m] + ctv*v0t[m] + ct1 + ce_*oet[m];
            sbse[m] = csx*x0[m]  + csv*v0[m]  + cs1 + ce2*oe[m];
            sbst[m] = csx*x0t[m] + csv*v0t[m] + cs1 + ce2*oet[m];
        }
    }

    // ================= sinkhorn0 -> s0 ===========================================
    float aq[16], att[16], u_, v_;
    sk_mult(t0q, t0t, q, r, sh_up, sh_vp, sh_rmp, aq, att, &u_, &v_);
    float s0v[16], s0t[16];
    {
        float vq[16], uq[16];
        ld16(sh_vp + 16*q, vq); ld16(sh_up + 16*q, uq);
        #pragma unroll
        for (int m = 0; m < 16; ++m) {
            s0v[m] = aq[m] * u_ * vq[m];
            s0t[m] = att[m] * uq[m] * v_;
        }
    }

    // ================= matvec B (v0, s0) -> t1, sacc =============================
    float ov[16], ovt[16], os[16], ost[16];
    matvec_dual(v0, v0t, s0v, s0t, mmq, dqv, mmt, dqt,
                ov, ovt, os, ost, q, r, sh_WR1, sh_WC1, sh_WR2, sh_WC2);
    float t1q[16], t1t[16], sacc[16], sacct[16];
    {
        float cts = sh_coef[5], cw_ = sh_coef[6], cu_ = sh_coef[7];
        float css = sh_coef[12], cw2 = sh_coef[13], cu2 = sh_coef[14];
        #pragma unroll
        for (int m = 0; m < 16; ++m) {
            t1q[m] = (t1b[m]  + cts*s0v[m] + cw_*ov[m]  + cu_*os[m])  * SK_SCALE;
            t1t[m] = (t1bt[m] + cts*s0t[m] + cw_*ovt[m] + cu_*ost[m]) * SK_SCALE;
            sacc[m]  = sbse[m] + css*s0v[m] + cw2*ov[m]  + cu2*os[m];
            sacct[m] = sbst[m] + css*s0t[m] + cw2*ovt[m] + cu2*ost[m];
        }
    }

    // ================= sinkhorn1 -> sacc += c17*s1 ===============================
    sk_mult(t1q, t1t, q, r, sh_up, sh_vp, sh_rmp, aq, att, &u_, &v_);
    {
        float c17 = sh_coef[17];
        float vq[16], uq[16];
        ld16(sh_vp + 16*q, vq); ld16(sh_up + 16*q, uq);
        #pragma unroll
        for (int m = 0; m < 16; ++m) {
            sacc[m]  += c17 * aq[m] * u_ * vq[m];
            sacct[m] += c17 * att[m] * uq[m] * v_;
        }
    }
    __syncthreads();   // protect up/vp reads before sinkhorn2 overwrites

    // ================= sinkhorn2 on s = sacc^T -> output =========================
    {
        float t2q[16], t2t[16];
        #pragma unroll
        for (int m = 0; m < 16; ++m) {
            t2q[m] = sacct[m] * SK_SCALE;   // s[r][16q+m] = Sc(16q+m, r)
            t2t[m] = sacc[m] * SK_SCALE;
        }
        sk_mult(t2q, t2t, q, r, sh_up, sh_vp, sh_rmp, aq, att, &u_, &v_);
        float vq[16]; ld16(sh_vp + 16*q, vq);
        #pragma unroll
        for (int t = 0; t < 4; ++t) {
            float4 o4;
            o4.x = aq[4*t+0] * u_ * vq[4*t+0];
            o4.y = aq[4*t+1] * u_ * vq[4*t+1];
            o4.z = aq[4*t+2] * u_ * vq[4*t+2];
            o4.w = aq[4*t+3] * u_ * vq[4*t+3];
            *(float4*)(out + r*64 + 16*q + 4*t) = o4;
        }
    }
}

extern "C" void kernel_launch(void* const* d_in, const int* in_sizes, int n_in,
                              void* d_out, int out_size, void* d_ws, size_t ws_size,
                              hipStream_t stream) {
    const float* ego = (const float*)d_in[0];
    const float* cav = (const float*)d_in[1];
    const float* nw1 = (const float*)d_in[2];
    const float* nb1 = (const float*)d_in[3];
    const float* nw2 = (const float*)d_in[4];
    const float* nb2 = (const float*)d_in[5];
    // d_in[6..9] = edge MLP weights: dead code (edge values only feed the (K!=0) pattern)
    const float* sw0 = (const float*)d_in[10];
    const float* sb0 = (const float*)d_in[11];
    const float* cw0 = (const float*)d_in[12];
    const float* cb0 = (const float*)d_in[13];
    const float* kw0 = (const float*)d_in[14];
    const float* kb0 = (const float*)d_in[15];
    const float* sw1 = (const float*)d_in[16];
    const float* sb1 = (const float*)d_in[17];
    const float* cw1 = (const float*)d_in[18];
    const float* cb1 = (const float*)d_in[19];
    const float* kw1 = (const float*)d_in[20];
    const float* kb1 = (const float*)d_in[21];
    const float* fcw = (const float*)d_in[22];
    const float* fcb = (const float*)d_in[23];

    gcn_match_kernel<<<dim3(1), dim3(256), 0, stream>>>(
        ego, cav, nw1, nb1, nw2, nb2,
        sw0, sb0, cw0, cb0, kw0, kb0,
        sw1, sb1, cw1, cb1, kw1, kb1,
        fcw, fcb, (float*)d_out);
}